// Round 5
// baseline (5949.031 us; speedup 1.0000x reference)
//
#include <hip/hip_runtime.h>
#include <hip/hip_bf16.h>

// LSTM SEQ=512, B=64, IN=1024, HID=1024.
// Round 15: R14 protocol (per-wave flags, early release), new decomposition:
//  - 32 recurrence blocks x 128 gate-cols (was 128 x 32): h-broadcast drops
//    16MB -> 4MB/step (the MALL-congestion term R13/R14 isolated).
//  - Per-wave weight slice (32 gate-cols x 1024) lives in 256 VGPRs for all
//    512 steps (zero weight traffic; LDS now only h chunk-ring + G).
//  - h chunk staged per batch-quarter by each wave (ASTAGE verbatim), but all
//    waves read all quarters -> per-chunk vmcnt ladder + s_barrier (8/step).
//    Ring-slot safety: chunk kc+3 staged only AFTER barrier kc (all waves
//    provably done reading that slot's previous chunk).
//  - Gates: lane = batch, 8 h-cols per lane; G[64][129] f32 scalar access
//    (conflict-free, own-wave columns -> no barrier before gate read).
//  - 224 GEMM workers (verbatim R14 worker, wid = bid-32, stride 224).

typedef __attribute__((ext_vector_type(8))) short short8;
typedef __attribute__((ext_vector_type(4))) float f32x4;
typedef __attribute__((ext_vector_type(4))) unsigned int u32x4;

#define SEQ  512
#define NBAT 64
#define RING 128

static __device__ __forceinline__ unsigned short f2b(float f) {
  unsigned u = __float_as_uint(f);
  unsigned r = (u + 0x7fffu + ((u >> 16) & 1u)) >> 16;
  return (unsigned short)r;
}

static __device__ __forceinline__ void gld_lds16(const void* g, void* l) {
  __builtin_amdgcn_global_load_lds((const __attribute__((address_space(1))) void*)g,
                                   (__attribute__((address_space(3))) void*)l, 16, 0, 0);
}
static __device__ __forceinline__ void gld_lds16_sc1(const void* g, void* l) {
  __builtin_amdgcn_global_load_lds((const __attribute__((address_space(1))) void*)g,
                                   (__attribute__((address_space(3))) void*)l, 16, 0, 16);
}

static __device__ __forceinline__ float sigf(float x) { return 1.f / (1.f + __expf(-x)); }
static __device__ __forceinline__ float tanhfast(float x) { return 1.f - 2.f / (1.f + __expf(2.f * x)); }

// ---------------- prep kernels ----------------

__global__ __launch_bounds__(512) void pack_w(const float* __restrict__ Wf,
                                              const float* __restrict__ Wi,
                                              const float* __restrict__ Wo,
                                              const float* __restrict__ Wc,
                                              unsigned short* __restrict__ Wht,
                                              unsigned short* __restrict__ Wxt) {
  __shared__ float tile[64][65];
  int bx = blockIdx.x;
  int g  = bx & 3; bx >>= 2;
  int jb = bx & 15;
  int kb = bx >> 4;
  int j0 = jb * 64, k0 = kb * 64;
  const float* W = (g == 0) ? Wf : (g == 1) ? Wi : (g == 2) ? Wo : Wc;
  int t = threadIdx.x;
  {
    int r  = t >> 3;
    int c0 = (t & 7) * 8;
    const float* src = W + (size_t)(k0 + r) * 1024 + j0 + c0;
    float4 a = *(const float4*)src;
    float4 b = *(const float4*)(src + 4);
    tile[r][c0 + 0] = a.x; tile[r][c0 + 1] = a.y; tile[r][c0 + 2] = a.z; tile[r][c0 + 3] = a.w;
    tile[r][c0 + 4] = b.x; tile[r][c0 + 5] = b.y; tile[r][c0 + 6] = b.z; tile[r][c0 + 7] = b.w;
  }
  __syncthreads();
  {
    int jj  = t >> 3;
    int cc8 = t & 7;
    unsigned short v[8];
#pragma unroll
    for (int e = 0; e < 8; ++e) v[e] = f2b(tile[cc8 * 8 + e][jj]);
    size_t p = (size_t)(4 * (j0 + jj) + g);
    if (k0 < 1024)
      *(uint4*)(&Wht[p * 1024 + k0 + cc8 * 8]) = *(const uint4*)v;
    else
      *(uint4*)(&Wxt[p * 1024 + (k0 - 1024) + cc8 * 8]) = *(const uint4*)v;
  }
}

__global__ __launch_bounds__(256) void pack_bias(const float* __restrict__ bf,
                                                 const float* __restrict__ bi,
                                                 const float* __restrict__ bo,
                                                 const float* __restrict__ bc,
                                                 float* __restrict__ bp) {
  int p = blockIdx.x * 256 + threadIdx.x;
  if (p < 4096) {
    int j = p >> 2, g = p & 3;
    const float* b = (g == 0) ? bf : (g == 1) ? bi : (g == 2) ? bo : bc;
    bp[p] = b[j];
  }
}

__global__ __launch_bounds__(256) void conv_x(const float* __restrict__ x,
                                              unsigned short* __restrict__ xb, int n8) {
  int i = blockIdx.x * 256 + threadIdx.x;
  if (i < n8) {
    const float4* xp = (const float4*)x + (size_t)i * 2;
    float4 a = xp[0], b = xp[1];
    unsigned short v[8] = {f2b(a.x), f2b(a.y), f2b(a.z), f2b(a.w),
                           f2b(b.x), f2b(b.y), f2b(b.z), f2b(b.w)};
    *(uint4*)(&xb[(size_t)i * 8]) = *(const uint4*)v;
  }
}

// zero hA, cst, flagw, gxcnt, flags4
__global__ __launch_bounds__(256) void init_state(unsigned short* __restrict__ hA,
                                                  float* __restrict__ c,
                                                  int* __restrict__ flagw,
                                                  int* __restrict__ gxcnt,
                                                  int* __restrict__ flags4) {
  int i = blockIdx.x * 256 + threadIdx.x;
  if (i < NBAT * 1024) { hA[i] = 0; c[i] = 0.f; }
  if (i < 128) flagw[i] = 0;
  if (i < 256) gxcnt[i] = 0;
  if (i < 4)   flags4[i] = 0;
}

// ---------------- fused persistent kernel ----------------
// grid 256 x 256 thr; LDS 98.6 KB -> 1 block/CU -> all 256 blocks co-resident.

__global__ __launch_bounds__(256, 1) void lstm_fused(
    const unsigned short* __restrict__ Wht,   // [4096][1024] bf16, p = 4*j+g
    const unsigned short* __restrict__ Wxt,   // [4096][1024] bf16
    const float* __restrict__ bp,             // [4096] packed bias
    const unsigned short* __restrict__ xb,    // [512][64][1024] bf16
    float* __restrict__ GxRing,               // [RING][64][4096] fp32
    unsigned short* __restrict__ hA,
    unsigned short* __restrict__ hB,
    float* __restrict__ cst,
    float* __restrict__ out,                  // [512][64][1024] fp32
    float* __restrict__ outH,
    float* __restrict__ outC,
    int* __restrict__ flagw,                  // [4*32] per-wave-lane flags (w*32+blk)
    int* __restrict__ gxcnt,                  // [256]
    int* __restrict__ flags4) {               // [4] block-0 per-wave progress
  __shared__ __align__(16) char lds[98560];

  const int tid = threadIdx.x;
  const int bid = blockIdx.x;
  const int lane = tid & 63;

  if (bid < 32) {
    // ================= recurrence role =================
    char* Ab        = lds;                            // ring4 x [4 quarters x 4KB] = 64KB
    float (*G)[129] = (float(*)[129])(lds + 65536);   // [64][129] f32, 33KB

    const int w    = tid >> 6;
    const int rl   = lane & 15;
    const int kb   = lane >> 4;
    const int p0   = bid * 128;            // packed gate-col base of block
    const int colb = bid * 32 + w * 8;     // h-col base of this wave's lanes

    // ---- Ws preload: wave's 32 gate-cols x 1024 k, 256 VGPRs, all steps ----
    short8 wreg[64];
#pragma unroll
    for (int n = 0; n < 2; ++n) {
      const unsigned short* wp = Wht + (size_t)(p0 + w * 32 + n * 16 + rl) * 1024 + kb * 8;
#pragma unroll
      for (int ki = 0; ki < 32; ++ki)
        wreg[n * 32 + ki] = *(const short8*)(wp + ki * 32);
    }

    // ---- c state: lane = batch, cols [colb, colb+8) ----
    float cr[8];
    {
      const float* cp = cst + (size_t)lane * 1024 + colb;
      f32x4 a = *(const f32x4*)cp, b = *(const f32x4*)(cp + 4);
      cr[0] = a[0]; cr[1] = a[1]; cr[2] = a[2]; cr[3] = a[3];
      cr[4] = b[0]; cr[5] = b[1]; cr[6] = b[2]; cr[7] = b[3];
    }

    asm volatile("s_waitcnt vmcnt(0)" ::: "memory");
    __syncthreads();   // one-time

#define ASTAGE(c_)                                                             \
    {                                                                          \
      const unsigned short* hrow = hsrc + (size_t)(w * 16) * 1024 + (c_) * 128;\
      char* dbase = Ab + ((c_) & 3) * 16384 + w * 4096;                        \
      _Pragma("unroll") for (int i = 0; i < 4; ++i) {                          \
        int s = i * 64 + lane;                                                 \
        int row_loc = s >> 4;                                                  \
        int slot = s & 15;                                                     \
        int src = slot ^ (row_loc & 7);                                        \
        gld_lds16_sc1(hrow + (size_t)row_loc * 1024 + src * 8,                 \
                      dbase + i * 1024);                                       \
      }                                                                        \
    }

    for (int t = 0; t < SEQ; ++t) {
      const unsigned short* hsrc = (t & 1) ? hB : hA;
      unsigned short*       hdst = (t & 1) ? hA : hB;

      // ---- poll: all 4x32 wave flags + coarse Gx count ----
      {
        while (true) {
          int m0 = __hip_atomic_load(&flagw[lane * 2],     __ATOMIC_RELAXED, __HIP_MEMORY_SCOPE_AGENT);
          int m1 = __hip_atomic_load(&flagw[lane * 2 + 1], __ATOMIC_RELAXED, __HIP_MEMORY_SCOPE_AGENT);
          int cg = __hip_atomic_load(&gxcnt[t >> 1],       __ATOMIC_RELAXED, __HIP_MEMORY_SCOPE_AGENT);
          if (__all((m0 >= t) && (m1 >= t) && (cg >= 32))) break;
          __builtin_amdgcn_s_sleep(1);
        }
      }
      __builtin_amdgcn_sched_barrier(0);

      // ---- Gx: 8 dwordx4 sc1 (oldest vmem ops of the step) ----
      u32x4 gx[8];
      {
        const float* gsrc = GxRing + (size_t)(t & (RING - 1)) * 262144 +
                            (size_t)lane * 4096 + p0 + w * 32;
        asm volatile("global_load_dwordx4 %0, %1, off sc1"           : "=v"(gx[0]) : "v"(gsrc));
        asm volatile("global_load_dwordx4 %0, %1, off offset:16 sc1" : "=v"(gx[1]) : "v"(gsrc));
        asm volatile("global_load_dwordx4 %0, %1, off offset:32 sc1" : "=v"(gx[2]) : "v"(gsrc));
        asm volatile("global_load_dwordx4 %0, %1, off offset:48 sc1" : "=v"(gx[3]) : "v"(gsrc));
        asm volatile("global_load_dwordx4 %0, %1, off offset:64 sc1" : "=v"(gx[4]) : "v"(gsrc));
        asm volatile("global_load_dwordx4 %0, %1, off offset:80 sc1" : "=v"(gx[5]) : "v"(gsrc));
        asm volatile("global_load_dwordx4 %0, %1, off offset:96 sc1" : "=v"(gx[6]) : "v"(gsrc));
        asm volatile("global_load_dwordx4 %0, %1, off offset:112 sc1": "=v"(gx[7]) : "v"(gsrc));
      }
      __builtin_amdgcn_sched_barrier(0);

      // ---- staging prologue: chunks 0..3 (each wave its batch-quarter) ----
      ASTAGE(0); ASTAGE(1); ASTAGE(2); ASTAGE(3);

      f32x4 acc[4][2];
#pragma unroll
      for (int mq = 0; mq < 4; ++mq)
#pragma unroll
        for (int n = 0; n < 2; ++n) acc[mq][n] = (f32x4){0.f, 0.f, 0.f, 0.f};

#pragma unroll
      for (int kc = 0; kc < 8; ++kc) {
        if      (kc == 0) asm volatile("s_waitcnt vmcnt(12)" ::: "memory");
        else if (kc <= 5) asm volatile("s_waitcnt vmcnt(8)"  ::: "memory");
        else if (kc == 6) asm volatile("s_waitcnt vmcnt(4)"  ::: "memory");
        else              asm volatile("s_waitcnt vmcnt(0)"  ::: "memory");
        __builtin_amdgcn_sched_barrier(0);
        __builtin_amdgcn_s_barrier();            // all waves' chunk kc staged
        __builtin_amdgcn_sched_barrier(0);
        if (kc >= 1 && kc <= 4) ASTAGE(kc + 3);  // slot of chunk kc-1: safe past barrier kc
        const char* Abc = Ab + (kc & 3) * 16384;
#pragma unroll
        for (int ks = 0; ks < 4; ++ks) {
          const int g = ks * 4 + kb;
          const int ao = rl * 256 + ((g ^ (rl & 7)) * 16);
          short8 af0 = *(const short8*)(Abc +     0 + ao);
          short8 af1 = *(const short8*)(Abc +  4096 + ao);
          short8 af2 = *(const short8*)(Abc +  8192 + ao);
          short8 af3 = *(const short8*)(Abc + 12288 + ao);
          const short8 b0 = wreg[kc * 4 + ks];
          const short8 b1 = wreg[32 + kc * 4 + ks];
          acc[0][0] = __builtin_amdgcn_mfma_f32_16x16x32_bf16(af0, b0, acc[0][0], 0, 0, 0);
          acc[0][1] = __builtin_amdgcn_mfma_f32_16x16x32_bf16(af0, b1, acc[0][1], 0, 0, 0);
          acc[1][0] = __builtin_amdgcn_mfma_f32_16x16x32_bf16(af1, b0, acc[1][0], 0, 0, 0);
          acc[1][1] = __builtin_amdgcn_mfma_f32_16x16x32_bf16(af1, b1, acc[1][1], 0, 0, 0);
          acc[2][0] = __builtin_amdgcn_mfma_f32_16x16x32_bf16(af2, b0, acc[2][0], 0, 0, 0);
          acc[2][1] = __builtin_amdgcn_mfma_f32_16x16x32_bf16(af2, b1, acc[2][1], 0, 0, 0);
          acc[3][0] = __builtin_amdgcn_mfma_f32_16x16x32_bf16(af3, b0, acc[3][0], 0, 0, 0);
          acc[3][1] = __builtin_amdgcn_mfma_f32_16x16x32_bf16(af3, b1, acc[3][1], 0, 0, 0);
        }
      }

      // ---- acc -> G (wave's 32-col stripe, all 64 rows; own-wave only) ----
#pragma unroll
      for (int mq = 0; mq < 4; ++mq)
#pragma unroll
        for (int n = 0; n < 2; ++n)
#pragma unroll
          for (int r = 0; r < 4; ++r)
            G[mq * 16 + kb * 4 + r][w * 32 + n * 16 + rl] = acc[mq][n][r];

      // ---- gates: lane = batch, 8 h-cols ----
      float h8[8];
      {
        const float* Gr = &G[lane][w * 32];
#pragma unroll
        for (int j = 0; j < 8; ++j) {
          f32x4 q = __builtin_bit_cast(f32x4, gx[j]);
          float f = sigf(Gr[4 * j + 0] + q[0]);
          float i = sigf(Gr[4 * j + 1] + q[1]);
          float o = sigf(Gr[4 * j + 2] + q[2]);
          float qq = tanhfast(Gr[4 * j + 3] + q[3]);
          cr[j] = cr[j] * f + qq * i;
          h8[j] = tanhfast(cr[j]) * o;
        }
      }

      // ---- release: h publish (sc1) -> ack -> per-wave flag ----
      {
        u32x4 hp;
#pragma unroll
        for (int d = 0; d < 4; ++d)
          hp[d] = ((unsigned)f2b(h8[2 * d + 1]) << 16) | (unsigned)f2b(h8[2 * d]);
        unsigned short* hd = hdst + (size_t)lane * 1024 + colb;
        asm volatile("global_store_dwordx4 %0, %1, off sc1" :: "v"(hd), "v"(hp) : "memory");
      }
      asm volatile("s_waitcnt vmcnt(0)" ::: "memory");
      if (lane == 0) {
        __hip_atomic_store(&flagw[w * 32 + bid], t + 1, __ATOMIC_RELAXED, __HIP_MEMORY_SCOPE_AGENT);
        if (bid == 0)
          __hip_atomic_store(&flags4[w], t + 1, __ATOMIC_RELAXED, __HIP_MEMORY_SCOPE_AGENT);
      }

      // off the critical path: out / tails (drained by next poll's waitcnt)
      {
        float* op = out + (size_t)t * 65536 + (size_t)lane * 1024 + colb;
        f32x4 o0, o1;
        o0[0] = h8[0]; o0[1] = h8[1]; o0[2] = h8[2]; o0[3] = h8[3];
        o1[0] = h8[4]; o1[1] = h8[5]; o1[2] = h8[6]; o1[3] = h8[7];
        *(f32x4*)op = o0; *(f32x4*)(op + 4) = o1;
        if (t == SEQ - 1) {
          float* hp2 = outH + (size_t)lane * 1024 + colb;
          float* cp2 = outC + (size_t)lane * 1024 + colb;
          *(f32x4*)hp2 = o0; *(f32x4*)(hp2 + 4) = o1;
          f32x4 c0v, c1v;
          c0v[0] = cr[0]; c0v[1] = cr[1]; c0v[2] = cr[2]; c0v[3] = cr[3];
          c1v[0] = cr[4]; c1v[1] = cr[5]; c1v[2] = cr[6]; c1v[3] = cr[7];
          *(f32x4*)cp2 = c0v; *(f32x4*)(cp2 + 4) = c1v;
        }
      }
    }
#undef ASTAGE

    {
      float* cp = cst + (size_t)lane * 1024 + colb;
      f32x4 c0v, c1v;
      c0v[0] = cr[0]; c0v[1] = cr[1]; c0v[2] = cr[2]; c0v[3] = cr[3];
      c1v[0] = cr[4]; c1v[1] = cr[5]; c1v[2] = cr[6]; c1v[3] = cr[7];
      *(f32x4*)cp = c0v; *(f32x4*)(cp + 4) = c1v;
    }

  } else {
    // ================= GEMM worker role =================
    unsigned short* AsW = (unsigned short*)lds;            // [2][8192]
    unsigned short* BsW = (unsigned short*)(lds + 32768);  // [2][8192]
    const int wid = bid - 32;
    const int w = tid >> 6;
    const int rl = lane & 15, kb = lane >> 4;
    const int wr = w >> 1, wc = w & 1;

    for (int tau = wid; tau < 8192; tau += 224) {
      int sp = tau >> 5;         // step pair 0..255
      int bn = tau & 31;         // 128-col tile

      // ring-overwrite gate (margin 16 steps; min over per-wave progress)
      if (2 * sp >= RING - 16) {
        int need = 2 * sp - (RING - 16) + 1;
        while (true) {
          int v = __hip_atomic_load(&flags4[lane & 3], __ATOMIC_RELAXED, __HIP_MEMORY_SCOPE_AGENT);
          if (__all(v >= need)) break;
          __builtin_amdgcn_s_sleep(16);
        }
      }

      const unsigned short* Abase = xb + (size_t)sp * 131072;
      const unsigned short* Bbase = Wxt + (size_t)bn * 131072;

      f32x4 acc[4][4];
#pragma unroll
      for (int m = 0; m < 4; ++m)
#pragma unroll
        for (int n = 0; n < 4; ++n) acc[m][n] = (f32x4){0.f, 0.f, 0.f, 0.f};

#define GSTAGE(k0_, buf_)                                                       \
      {                                                                         \
        _Pragma("unroll") for (int r = 0; r < 4; ++r) {                         \
          int i = r * 256 + tid;                                                \
          int row = i >> 3;                                                     \
          int cc = (i & 7) ^ (row & 7);                                         \
          int base = (r * 256 + (tid & 192)) * 8;                               \
          gld_lds16(Abase + (size_t)row * 1024 + (k0_) + cc * 8, &AsW[(buf_)*8192 + base]); \
          gld_lds16(Bbase + (size_t)row * 1024 + (k0_) + cc * 8, &BsW[(buf_)*8192 + base]); \
        }                                                                       \
      }

      GSTAGE(0, 0);
      __syncthreads();
      int cur = 0;
#pragma unroll 2
      for (int kc = 0; kc < 16; ++kc) {
        if (kc < 15) GSTAGE((kc + 1) * 64, cur ^ 1);
        const char* Abt = (const char*)&AsW[cur * 8192];
        const char* Bbt = (const char*)&BsW[cur * 8192];
#pragma unroll
        for (int ks = 0; ks < 2; ++ks) {
          int g = ks * 4 + kb;
          short8 bf[4], af[4];
#pragma unroll
          for (int nt = 0; nt < 4; ++nt) {
            int brow = wc * 64 + nt * 16 + rl;
            bf[nt] = *(const short8*)(Bbt + brow * 128 + ((g ^ (brow & 7)) * 16));
          }
#pragma unroll
          for (int mt = 0; mt < 4; ++mt) {
            int arow = wr * 64 + mt * 16 + rl;
            af[mt] = *(const short8*)(Abt + arow * 128 + ((g ^ (arow & 7)) * 16));
          }
#pragma unroll
          for (int mt = 0; mt < 4; ++mt)
#pragma unroll
            for (int nt = 0; nt < 4; ++nt)
              acc[mt][nt] = __builtin_amdgcn_mfma_f32_16x16x32_bf16(af[mt], bf[nt], acc[mt][nt], 0, 0, 0);
        }
        __syncthreads();
        cur ^= 1;
      }
#undef GSTAGE

      // epilogue: device-scope stores into the ring (+bias)
      float* Cb = GxRing + (size_t)((2 * sp) & (RING - 1)) * 262144;
#pragma unroll
      for (int nt = 0; nt < 4; ++nt) {
        int p = bn * 128 + wc * 64 + nt * 16 + rl;
        float bias = bp[p];
#pragma unroll
        for (int mt = 0; mt < 4; ++mt) {
#pragma unroll
          for (int r = 0; r < 4; ++r) {
            int row = wr * 64 + mt * 16 + kb * 4 + r;   // 0..127 within the pair
            __hip_atomic_store(&Cb[(size_t)row * 4096 + p], acc[mt][nt][r] + bias,
                               __ATOMIC_RELAXED, __HIP_MEMORY_SCOPE_AGENT);
          }
        }
      }
      asm volatile("s_waitcnt vmcnt(0)" ::: "memory");
      __syncthreads();
      if (tid == 0)
        __hip_atomic_fetch_add(&gxcnt[sp], 1, __ATOMIC_RELAXED, __HIP_MEMORY_SCOPE_AGENT);
    }
  }
}

// ---------------- launch ----------------

extern "C" void kernel_launch(void* const* d_in, const int* in_sizes, int n_in,
                              void* d_out, int out_size, void* d_ws, size_t ws_size,
                              hipStream_t stream) {
  const float* x  = (const float*)d_in[0];
  const float* Wf = (const float*)d_in[1];
  const float* bf = (const float*)d_in[2];
  const float* Wi = (const float*)d_in[3];
  const float* bi = (const float*)d_in[4];
  const float* Wo = (const float*)d_in[5];
  const float* bo = (const float*)d_in[6];
  const float* Wc = (const float*)d_in[7];
  const float* bc = (const float*)d_in[8];
  float* out = (float*)d_out;

  char* ws = (char*)d_ws;
  unsigned short* Wht = (unsigned short*)(ws);                 //  8,388,608
  unsigned short* Wxt = (unsigned short*)(ws + 8388608);       //  8,388,608
  float*          bp  = (float*)(ws + 16777216);               //     16,384
  unsigned short* xb  = (unsigned short*)(ws + 16793600);      // 67,108,864
  unsigned short* hA  = (unsigned short*)(ws + 83902464);      //    131,072
  unsigned short* hB  = (unsigned short*)(ws + 84033536);      //    131,072
  float*          cst = (float*)(ws + 84164608);               //    262,144
  int*            flw = (int*)(ws + 84426752);                 //        512 (pad 4K)
  int*            gxc = (int*)(ws + 84430848);                 //      1,024
  int*            fl4 = (int*)(ws + 84431872);                 //         16 (pad to 84440064)
  float*          GxR = (float*)(ws + 84440064);               // 134,217,728

  pack_w    <<<2048,  512, 0, stream>>>(Wf, Wi, Wo, Wc, Wht, Wxt);
  pack_bias <<<16,    256, 0, stream>>>(bf, bi, bo, bc, bp);
  conv_x    <<<16384, 256, 0, stream>>>(x, xb, 4194304);
  init_state<<<256,   256, 0, stream>>>(hA, cst, flw, gxc, fl4);

  float* outH = out + (size_t)SEQ * NBAT * 1024;
  float* outC = outH + NBAT * 1024;

  lstm_fused<<<256, 256, 0, stream>>>(Wht, Wxt, bp, xb, GxR, hA, hB, cst,
                                      out, outH, outC, flw, gxc, fl4);
}

// Round 6
// 3345.745 us; speedup vs baseline: 1.7781x; 1.7781x over previous
//
#include <hip/hip_runtime.h>
#include <hip/hip_bf16.h>

// LSTM SEQ=512, B=64, IN=1024, HID=1024.
// Round 16: R14 protocol VERBATIM (per-wave flags, early release, no barriers,
// wave-independent ladder), new decomposition: 64 recurrence blocks x 64
// gate-cols (was 128 x 32). Halves the h-broadcast 16MB -> 8MB/step (the
// aggregate-MALL term), keeps per-CU staging identical (128KB/step/block).
//  - Block's 64 pcols split: lower 32 in LDS Ws (same swizzled layout/staging
//    as R14), upper 32 as 64 short8 B-frags in registers per wave (loaded
//    once, reused all 512 steps; AGPR-eligible -> no LDS growth, R15 proved
//    the preload correct).
//  - Per (kc,ks): 4 MFMAs (2 LDS B-frags + 2 reg B-frags), 128/step/wave.
//  - Gates: thread = (batch gb, 4 h-cols); Gx = 4 dwordx4; publish dwordx2.
//  - Poll: 64 producer flags = 1 per lane (was 2) + coarse gxcnt.
//  - Workers: 192 blocks (bid>=64), stride 192, verbatim otherwise.

typedef __attribute__((ext_vector_type(8))) short short8;
typedef __attribute__((ext_vector_type(4))) float f32x4;
typedef __attribute__((ext_vector_type(4))) unsigned int u32x4;
typedef __attribute__((ext_vector_type(2))) unsigned int u32x2;

#define SEQ  512
#define NBAT 64
#define RING 128

static __device__ __forceinline__ unsigned short f2b(float f) {
  unsigned u = __float_as_uint(f);
  unsigned r = (u + 0x7fffu + ((u >> 16) & 1u)) >> 16;
  return (unsigned short)r;
}

static __device__ __forceinline__ void gld_lds16(const void* g, void* l) {
  __builtin_amdgcn_global_load_lds((const __attribute__((address_space(1))) void*)g,
                                   (__attribute__((address_space(3))) void*)l, 16, 0, 0);
}
static __device__ __forceinline__ void gld_lds16_sc1(const void* g, void* l) {
  __builtin_amdgcn_global_load_lds((const __attribute__((address_space(1))) void*)g,
                                   (__attribute__((address_space(3))) void*)l, 16, 0, 16);
}

static __device__ __forceinline__ float sigf(float x) { return 1.f / (1.f + __expf(-x)); }
static __device__ __forceinline__ float tanhfast(float x) { return 1.f - 2.f / (1.f + __expf(2.f * x)); }

// ---------------- prep kernels ----------------

__global__ __launch_bounds__(512) void pack_w(const float* __restrict__ Wf,
                                              const float* __restrict__ Wi,
                                              const float* __restrict__ Wo,
                                              const float* __restrict__ Wc,
                                              unsigned short* __restrict__ Wht,
                                              unsigned short* __restrict__ Wxt) {
  __shared__ float tile[64][65];
  int bx = blockIdx.x;
  int g  = bx & 3; bx >>= 2;
  int jb = bx & 15;
  int kb = bx >> 4;
  int j0 = jb * 64, k0 = kb * 64;
  const float* W = (g == 0) ? Wf : (g == 1) ? Wi : (g == 2) ? Wo : Wc;
  int t = threadIdx.x;
  {
    int r  = t >> 3;
    int c0 = (t & 7) * 8;
    const float* src = W + (size_t)(k0 + r) * 1024 + j0 + c0;
    float4 a = *(const float4*)src;
    float4 b = *(const float4*)(src + 4);
    tile[r][c0 + 0] = a.x; tile[r][c0 + 1] = a.y; tile[r][c0 + 2] = a.z; tile[r][c0 + 3] = a.w;
    tile[r][c0 + 4] = b.x; tile[r][c0 + 5] = b.y; tile[r][c0 + 6] = b.z; tile[r][c0 + 7] = b.w;
  }
  __syncthreads();
  {
    int jj  = t >> 3;
    int cc8 = t & 7;
    unsigned short v[8];
#pragma unroll
    for (int e = 0; e < 8; ++e) v[e] = f2b(tile[cc8 * 8 + e][jj]);
    size_t p = (size_t)(4 * (j0 + jj) + g);
    if (k0 < 1024)
      *(uint4*)(&Wht[p * 1024 + k0 + cc8 * 8]) = *(const uint4*)v;
    else
      *(uint4*)(&Wxt[p * 1024 + (k0 - 1024) + cc8 * 8]) = *(const uint4*)v;
  }
}

__global__ __launch_bounds__(256) void pack_bias(const float* __restrict__ bf,
                                                 const float* __restrict__ bi,
                                                 const float* __restrict__ bo,
                                                 const float* __restrict__ bc,
                                                 float* __restrict__ bp) {
  int p = blockIdx.x * 256 + threadIdx.x;
  if (p < 4096) {
    int j = p >> 2, g = p & 3;
    const float* b = (g == 0) ? bf : (g == 1) ? bi : (g == 2) ? bo : bc;
    bp[p] = b[j];
  }
}

__global__ __launch_bounds__(256) void conv_x(const float* __restrict__ x,
                                              unsigned short* __restrict__ xb, int n8) {
  int i = blockIdx.x * 256 + threadIdx.x;
  if (i < n8) {
    const float4* xp = (const float4*)x + (size_t)i * 2;
    float4 a = xp[0], b = xp[1];
    unsigned short v[8] = {f2b(a.x), f2b(a.y), f2b(a.z), f2b(a.w),
                           f2b(b.x), f2b(b.y), f2b(b.z), f2b(b.w)};
    *(uint4*)(&xb[(size_t)i * 8]) = *(const uint4*)v;
  }
}

// zero hA, cst, flagw, gxcnt, flags4
__global__ __launch_bounds__(256) void init_state(unsigned short* __restrict__ hA,
                                                  float* __restrict__ c,
                                                  int* __restrict__ flagw,
                                                  int* __restrict__ gxcnt,
                                                  int* __restrict__ flags4) {
  int i = blockIdx.x * 256 + threadIdx.x;
  if (i < NBAT * 1024) { hA[i] = 0; c[i] = 0.f; }
  if (i < 256) flagw[i] = 0;
  if (i < 256) gxcnt[i] = 0;
  if (i < 4)   flags4[i] = 0;
}

// ---------------- fused persistent kernel ----------------
// grid 256 x 256 thr; LDS 144.3 KB -> 1 block/CU -> all 256 blocks co-resident.

__global__ __launch_bounds__(256, 1) void lstm_fused(
    const unsigned short* __restrict__ Wht,   // [4096][1024] bf16, p = 4*j+g
    const unsigned short* __restrict__ Wxt,   // [4096][1024] bf16
    const float* __restrict__ bp,             // [4096] packed bias
    const unsigned short* __restrict__ xb,    // [512][64][1024] bf16
    float* __restrict__ GxRing,               // [RING][64][4096] fp32
    unsigned short* __restrict__ hA,
    unsigned short* __restrict__ hB,
    float* __restrict__ cst,
    float* __restrict__ out,                  // [512][64][1024] fp32
    float* __restrict__ outH,
    float* __restrict__ outC,
    int* __restrict__ flagw,                  // [4][64] per-wave-lane flags
    int* __restrict__ gxcnt,                  // [256]
    int* __restrict__ flags4) {               // [4] block-0 per-wave progress
  __shared__ __align__(16) char lds[147712];

  const int tid = threadIdx.x;
  const int bid = blockIdx.x;
  const int lane = tid & 63;

  if (bid < 64) {
    // ================= recurrence role =================
    unsigned short* Ws = (unsigned short*)lds;           // [32 pcol][1024] swizzled, 64 KB
    char*           Ab = lds + 65536;                    // ring4 x 4 waves x 4KB, 64 KB
    float (*G)[65]     = (float(*)[65])(lds + 131072);   // [64][65] f32, 16.6 KB

    const int w   = tid >> 6;
    const int w16 = w * 16;
    const int rl  = lane & 15;
    const int kb  = lane >> 4;
    const int p0  = bid * 64;            // packed gate-col base of block

    // ---- stage Ws (lower 32 pcols) once; same swizzle as R14 ----
    {
      const unsigned short* Wsrc = Wht + (size_t)p0 * 1024;
#pragma unroll
      for (int r = 0; r < 16; ++r) {
        int s = r * 256 + tid;
        int row = s >> 7;
        int slot = s & 127;
        int sub = (slot & 7) ^ (row & 7);
        gld_lds16(Wsrc + (size_t)row * 1024 + ((slot & ~7) | sub) * 8,
                  Ws + (size_t)(r * 256 + (tid & 192)) * 8);
      }
    }

    // ---- upper 32 pcols: 64 B-frags in registers, all 512 steps ----
    short8 wreg[64];
#pragma unroll
    for (int n = 0; n < 2; ++n) {
      const unsigned short* wp = Wht + (size_t)(p0 + 32 + n * 16 + rl) * 1024 + kb * 8;
#pragma unroll
      for (int ki = 0; ki < 32; ++ki)
        wreg[n * 32 + ki] = *(const short8*)(wp + ki * 32);
    }

    // ---- c state: thread = (batch gb, 4 h-cols) ----
    const int gb   = tid >> 2;                       // batch; in [16w,16w+16)
    const int tl   = tid & 3;
    const int gidx = gb * 1024 + bid * 16 + tl * 4;  // h-col index (4 cols)
    float cr[4];
    {
      f32x4 cv = *(const f32x4*)(cst + gidx);
      cr[0] = cv[0]; cr[1] = cv[1]; cr[2] = cv[2]; cr[3] = cv[3];
    }

    asm volatile("s_waitcnt vmcnt(0)" ::: "memory");
    __syncthreads();   // one-time: Ws visible to all waves

#define ASTAGE(c_)                                                             \
    {                                                                          \
      const unsigned short* hrow = hsrc + (size_t)w16 * 1024 + (c_) * 128;     \
      char* dbase = Ab + ((c_) & 3) * 16384 + w * 4096;                        \
      _Pragma("unroll") for (int i = 0; i < 4; ++i) {                          \
        int s = i * 64 + lane;                                                 \
        int row_loc = s >> 4;                                                  \
        int slot = s & 15;                                                     \
        int src = slot ^ (row_loc & 7);                                        \
        gld_lds16_sc1(hrow + (size_t)row_loc * 1024 + src * 8,                 \
                      dbase + i * 1024);                                       \
      }                                                                        \
    }

    for (int t = 0; t < SEQ; ++t) {
      const unsigned short* hsrc = (t & 1) ? hB : hA;
      unsigned short*       hdst = (t & 1) ? hA : hB;

      // ---- readiness: each wave polls ITS lane's 64 flags + gxcnt ----
      {
        while (true) {
          int m  = __hip_atomic_load(&flagw[w * 64 + lane], __ATOMIC_RELAXED, __HIP_MEMORY_SCOPE_AGENT);
          int cg = __hip_atomic_load(&gxcnt[t >> 1],        __ATOMIC_RELAXED, __HIP_MEMORY_SCOPE_AGENT);
          if (__all((m >= t) && (cg >= 32))) break;
          __builtin_amdgcn_s_sleep(1);
        }
      }
      __builtin_amdgcn_sched_barrier(0);

      // ---- Gx loads: 4 dwordx4 sc1 (oldest vmem ops for the ladder) ----
      u32x4 gx0, gx1, gx2, gx3;
      {
        const float* gsrc = GxRing + (size_t)(t & (RING - 1)) * 262144 +
                            (size_t)gb * 4096 + p0 + tl * 16;
        asm volatile("global_load_dwordx4 %0, %1, off sc1"           : "=v"(gx0) : "v"(gsrc));
        asm volatile("global_load_dwordx4 %0, %1, off offset:16 sc1" : "=v"(gx1) : "v"(gsrc));
        asm volatile("global_load_dwordx4 %0, %1, off offset:32 sc1" : "=v"(gx2) : "v"(gsrc));
        asm volatile("global_load_dwordx4 %0, %1, off offset:48 sc1" : "=v"(gx3) : "v"(gsrc));
      }
      __builtin_amdgcn_sched_barrier(0);

      // ---- staging prologue: chunks 0..3 (wave-private, sc1) ----
      ASTAGE(0); ASTAGE(1); ASTAGE(2); ASTAGE(3);

      f32x4 acc0 = (f32x4){0.f, 0.f, 0.f, 0.f};
      f32x4 acc1 = (f32x4){0.f, 0.f, 0.f, 0.f};
      f32x4 acc2 = (f32x4){0.f, 0.f, 0.f, 0.f};
      f32x4 acc3 = (f32x4){0.f, 0.f, 0.f, 0.f};

#pragma unroll
      for (int kc = 0; kc < 8; ++kc) {
        if      (kc <= 4) asm volatile("s_waitcnt vmcnt(12)" ::: "memory");
        else if (kc == 5) asm volatile("s_waitcnt vmcnt(8)"  ::: "memory");
        else if (kc == 6) asm volatile("s_waitcnt vmcnt(4)"  ::: "memory");
        else              asm volatile("s_waitcnt vmcnt(0)"  ::: "memory");
        __builtin_amdgcn_sched_barrier(0);
        const char* Abc = Ab + (kc & 3) * 16384 + w * 4096;
#pragma unroll
        for (int ks = 0; ks < 4; ++ks) {
          int g = ks * 4 + kb;
          short8 af = *(const short8*)(Abc + rl * 256 + ((g ^ (rl & 7)) * 16));
          int gslot = kc * 16 + g;
          int gbase = (gslot & ~7) * 16;
          short8 bf0 = *(const short8*)((const char*)Ws + (0 * 16 + rl) * 2048 + gbase +
                                        (((gslot & 7) ^ (rl & 7)) * 16));
          short8 bf1 = *(const short8*)((const char*)Ws + (1 * 16 + rl) * 2048 + gbase +
                                        (((gslot & 7) ^ (rl & 7)) * 16));
          const short8 b2 = wreg[kc * 4 + ks];
          const short8 b3 = wreg[32 + kc * 4 + ks];
          acc0 = __builtin_amdgcn_mfma_f32_16x16x32_bf16(af, bf0, acc0, 0, 0, 0);
          acc1 = __builtin_amdgcn_mfma_f32_16x16x32_bf16(af, bf1, acc1, 0, 0, 0);
          acc2 = __builtin_amdgcn_mfma_f32_16x16x32_bf16(af, b2,  acc2, 0, 0, 0);
          acc3 = __builtin_amdgcn_mfma_f32_16x16x32_bf16(af, b3,  acc3, 0, 0, 0);
        }
        if (kc + 4 < 8) ASTAGE(kc + 4);
      }

      // ---- acc -> G (wave's 16 batches x 64 pcols; own-wave only) ----
#pragma unroll
      for (int r = 0; r < 4; ++r) {
        G[w16 + kb * 4 + r][ 0 + rl] = acc0[r];
        G[w16 + kb * 4 + r][16 + rl] = acc1[r];
        G[w16 + kb * 4 + r][32 + rl] = acc2[r];
        G[w16 + kb * 4 + r][48 + rl] = acc3[r];
      }

      // ---- gates: thread = (batch gb, 4 h-cols) ----
      float h4[4];
      {
        const float* Gr = &G[gb][tl * 16];
        f32x4 q0 = __builtin_bit_cast(f32x4, gx0);
        f32x4 q1 = __builtin_bit_cast(f32x4, gx1);
        f32x4 q2 = __builtin_bit_cast(f32x4, gx2);
        f32x4 q3 = __builtin_bit_cast(f32x4, gx3);
        float f, i, o, qq;
        f = sigf(Gr[ 0] + q0[0]); i = sigf(Gr[ 1] + q0[1]); o = sigf(Gr[ 2] + q0[2]); qq = tanhfast(Gr[ 3] + q0[3]);
        cr[0] = cr[0] * f + qq * i;  h4[0] = tanhfast(cr[0]) * o;
        f = sigf(Gr[ 4] + q1[0]); i = sigf(Gr[ 5] + q1[1]); o = sigf(Gr[ 6] + q1[2]); qq = tanhfast(Gr[ 7] + q1[3]);
        cr[1] = cr[1] * f + qq * i;  h4[1] = tanhfast(cr[1]) * o;
        f = sigf(Gr[ 8] + q2[0]); i = sigf(Gr[ 9] + q2[1]); o = sigf(Gr[10] + q2[2]); qq = tanhfast(Gr[11] + q2[3]);
        cr[2] = cr[2] * f + qq * i;  h4[2] = tanhfast(cr[2]) * o;
        f = sigf(Gr[12] + q3[0]); i = sigf(Gr[13] + q3[1]); o = sigf(Gr[14] + q3[2]); qq = tanhfast(Gr[15] + q3[3]);
        cr[3] = cr[3] * f + qq * i;  h4[3] = tanhfast(cr[3]) * o;
      }

      // ---- release: h publish (sc1 dwordx2) -> ack -> per-wave flag ----
      {
        u32x2 hp;
        hp[0] = ((unsigned)f2b(h4[1]) << 16) | (unsigned)f2b(h4[0]);
        hp[1] = ((unsigned)f2b(h4[3]) << 16) | (unsigned)f2b(h4[2]);
        unsigned short* hd = hdst + gidx;
        asm volatile("global_store_dwordx2 %0, %1, off sc1" :: "v"(hd), "v"(hp) : "memory");
      }
      asm volatile("s_waitcnt vmcnt(0)" ::: "memory");
      if (lane == 0) {
        __hip_atomic_store(&flagw[w * 64 + bid], t + 1, __ATOMIC_RELAXED, __HIP_MEMORY_SCOPE_AGENT);
        if (bid == 0)
          __hip_atomic_store(&flags4[w], t + 1, __ATOMIC_RELAXED, __HIP_MEMORY_SCOPE_AGENT);
      }

      // off the critical path: out / tails; drain before next step's ladder
      {
        f32x4 o0;
        o0[0] = h4[0]; o0[1] = h4[1]; o0[2] = h4[2]; o0[3] = h4[3];
        *(f32x4*)&out[(size_t)t * 65536 + gidx] = o0;
        if (t == SEQ - 1) {
          *(f32x4*)&outH[gidx] = o0;
          f32x4 cv; cv[0] = cr[0]; cv[1] = cr[1]; cv[2] = cr[2]; cv[3] = cr[3];
          *(f32x4*)&outC[gidx] = cv;
        }
      }
      asm volatile("s_waitcnt vmcnt(0)" ::: "memory");
    }
#undef ASTAGE

    {
      f32x4 cv; cv[0] = cr[0]; cv[1] = cr[1]; cv[2] = cr[2]; cv[3] = cr[3];
      *(f32x4*)&cst[gidx] = cv;
    }

  } else {
    // ================= GEMM worker role =================
    unsigned short* AsW = (unsigned short*)lds;            // [2][8192]
    unsigned short* BsW = (unsigned short*)(lds + 32768);  // [2][8192]
    const int wid = bid - 64;
    const int w = tid >> 6;
    const int rl = lane & 15, kb = lane >> 4;
    const int wr = w >> 1, wc = w & 1;

    for (int tau = wid; tau < 8192; tau += 192) {
      int sp = tau >> 5;         // step pair 0..255
      int bn = tau & 31;         // 128-col tile

      // ring-overwrite gate (margin 16 steps; min over per-wave progress)
      if (2 * sp >= RING - 16) {
        int need = 2 * sp - (RING - 16) + 1;
        while (true) {
          int v = __hip_atomic_load(&flags4[lane & 3], __ATOMIC_RELAXED, __HIP_MEMORY_SCOPE_AGENT);
          if (__all(v >= need)) break;
          __builtin_amdgcn_s_sleep(16);
        }
      }

      const unsigned short* Abase = xb + (size_t)sp * 131072;
      const unsigned short* Bbase = Wxt + (size_t)bn * 131072;

      f32x4 acc[4][4];
#pragma unroll
      for (int m = 0; m < 4; ++m)
#pragma unroll
        for (int n = 0; n < 4; ++n) acc[m][n] = (f32x4){0.f, 0.f, 0.f, 0.f};

#define GSTAGE(k0_, buf_)                                                       \
      {                                                                         \
        _Pragma("unroll") for (int r = 0; r < 4; ++r) {                         \
          int i = r * 256 + tid;                                                \
          int row = i >> 3;                                                     \
          int cc = (i & 7) ^ (row & 7);                                         \
          int base = (r * 256 + (tid & 192)) * 8;                               \
          gld_lds16(Abase + (size_t)row * 1024 + (k0_) + cc * 8, &AsW[(buf_)*8192 + base]); \
          gld_lds16(Bbase + (size_t)row * 1024 + (k0_) + cc * 8, &BsW[(buf_)*8192 + base]); \
        }                                                                       \
      }

      GSTAGE(0, 0);
      __syncthreads();
      int cur = 0;
#pragma unroll 2
      for (int kc = 0; kc < 16; ++kc) {
        if (kc < 15) GSTAGE((kc + 1) * 64, cur ^ 1);
        const char* Abt = (const char*)&AsW[cur * 8192];
        const char* Bbt = (const char*)&BsW[cur * 8192];
#pragma unroll
        for (int ks = 0; ks < 2; ++ks) {
          int g = ks * 4 + kb;
          short8 bf[4], af[4];
#pragma unroll
          for (int nt = 0; nt < 4; ++nt) {
            int brow = wc * 64 + nt * 16 + rl;
            bf[nt] = *(const short8*)(Bbt + brow * 128 + ((g ^ (brow & 7)) * 16));
          }
#pragma unroll
          for (int mt = 0; mt < 4; ++mt) {
            int arow = wr * 64 + mt * 16 + rl;
            af[mt] = *(const short8*)(Abt + arow * 128 + ((g ^ (arow & 7)) * 16));
          }
#pragma unroll
          for (int mt = 0; mt < 4; ++mt)
#pragma unroll
            for (int nt = 0; nt < 4; ++nt)
              acc[mt][nt] = __builtin_amdgcn_mfma_f32_16x16x32_bf16(af[mt], bf[nt], acc[mt][nt], 0, 0, 0);
        }
        __syncthreads();
        cur ^= 1;
      }
#undef GSTAGE

      // epilogue: device-scope stores into the ring (+bias)
      float* Cb = GxRing + (size_t)((2 * sp) & (RING - 1)) * 262144;
#pragma unroll
      for (int nt = 0; nt < 4; ++nt) {
        int p = bn * 128 + wc * 64 + nt * 16 + rl;
        float bias = bp[p];
#pragma unroll
        for (int mt = 0; mt < 4; ++mt) {
#pragma unroll
          for (int r = 0; r < 4; ++r) {
            int row = wr * 64 + mt * 16 + kb * 4 + r;   // 0..127 within the pair
            __hip_atomic_store(&Cb[(size_t)row * 4096 + p], acc[mt][nt][r] + bias,
                               __ATOMIC_RELAXED, __HIP_MEMORY_SCOPE_AGENT);
          }
        }
      }
      asm volatile("s_waitcnt vmcnt(0)" ::: "memory");
      __syncthreads();
      if (tid == 0)
        __hip_atomic_fetch_add(&gxcnt[sp], 1, __ATOMIC_RELAXED, __HIP_MEMORY_SCOPE_AGENT);
    }
  }
}

// ---------------- launch ----------------

extern "C" void kernel_launch(void* const* d_in, const int* in_sizes, int n_in,
                              void* d_out, int out_size, void* d_ws, size_t ws_size,
                              hipStream_t stream) {
  const float* x  = (const float*)d_in[0];
  const float* Wf = (const float*)d_in[1];
  const float* bf = (const float*)d_in[2];
  const float* Wi = (const float*)d_in[3];
  const float* bi = (const float*)d_in[4];
  const float* Wo = (const float*)d_in[5];
  const float* bo = (const float*)d_in[6];
  const float* Wc = (const float*)d_in[7];
  const float* bc = (const float*)d_in[8];
  float* out = (float*)d_out;

  char* ws = (char*)d_ws;
  unsigned short* Wht = (unsigned short*)(ws);                 //  8,388,608
  unsigned short* Wxt = (unsigned short*)(ws + 8388608);       //  8,388,608
  float*          bp  = (float*)(ws + 16777216);               //     16,384
  unsigned short* xb  = (unsigned short*)(ws + 16793600);      // 67,108,864
  unsigned short* hA  = (unsigned short*)(ws + 83902464);      //    131,072
  unsigned short* hB  = (unsigned short*)(ws + 84033536);      //    131,072
  float*          cst = (float*)(ws + 84164608);               //    262,144
  int*            flw = (int*)(ws + 84426752);                 //      1,024 (pad 4K)
  int*            gxc = (int*)(ws + 84430848);                 //      1,024
  int*            fl4 = (int*)(ws + 84431872);                 //         16 (pad to 84440064)
  float*          GxR = (float*)(ws + 84440064);               // 134,217,728

  pack_w    <<<2048,  512, 0, stream>>>(Wf, Wi, Wo, Wc, Wht, Wxt);
  pack_bias <<<16,    256, 0, stream>>>(bf, bi, bo, bc, bp);
  conv_x    <<<16384, 256, 0, stream>>>(x, xb, 4194304);
  init_state<<<256,   256, 0, stream>>>(hA, cst, flw, gxc, fl4);

  float* outH = out + (size_t)SEQ * NBAT * 1024;
  float* outC = outH + NBAT * 1024;

  lstm_fused<<<256, 256, 0, stream>>>(Wht, Wxt, bp, xb, GxR, hA, hB, cst,
                                      out, outH, outC, flw, gxc, fl4);
}

// Round 7
// 3052.365 us; speedup vs baseline: 1.9490x; 1.0961x over previous
//
#include <hip/hip_runtime.h>
#include <hip/hip_bf16.h>

// LSTM SEQ=512, B=64, IN=1024, HID=1024.
// Round 17: R14 VERBATIM (best measured, 2882us: per-wave flags, early
// release, wave-independent ladder), ONE mechanism changed: the h broadcast
// buffer is stored PRE-SWIZZLED in consumer-read order (m173 pattern).
//  - ASTAGE's gld_lds16 reads were 16B granules scattered at 2KB stride
//    (zero line locality): ~1M discrete 16B MALL requests per step -> the
//    per-step burst is request-rate bound, not byte bound (R13/R15/R16 all
//    cut bytes and regressed).
//  - Producers write the SAME dwords to permuted addresses: granule
//    (batch m, block b) lands in region (w=m>>4, c=b>>4) at entry
//    j = (m&15)*16 + ((b&15)^(m&7)). Consumers then ingest each chunk as
//    64 lanes x 16B CONTIGUOUS (1KB/instr) -> full line coalescing,
//    ~4-8x fewer MALL requests on the dominant stream.
//  - LDS image, instruction counts/order, vmcnt ladder, protocol, worker
//    role: all byte-identical to R14.

typedef __attribute__((ext_vector_type(8))) short short8;
typedef __attribute__((ext_vector_type(4))) float f32x4;
typedef __attribute__((ext_vector_type(4))) unsigned int u32x4;

#define SEQ  512
#define NBAT 64
#define RING 128

static __device__ __forceinline__ unsigned short f2b(float f) {
  unsigned u = __float_as_uint(f);
  unsigned r = (u + 0x7fffu + ((u >> 16) & 1u)) >> 16;
  return (unsigned short)r;
}

static __device__ __forceinline__ void gld_lds16(const void* g, void* l) {
  __builtin_amdgcn_global_load_lds((const __attribute__((address_space(1))) void*)g,
                                   (__attribute__((address_space(3))) void*)l, 16, 0, 0);
}
static __device__ __forceinline__ void gld_lds16_sc1(const void* g, void* l) {
  __builtin_amdgcn_global_load_lds((const __attribute__((address_space(1))) void*)g,
                                   (__attribute__((address_space(3))) void*)l, 16, 0, 16);
}

static __device__ __forceinline__ float sigf(float x) { return 1.f / (1.f + __expf(-x)); }
static __device__ __forceinline__ float tanhfast(float x) { return 1.f - 2.f / (1.f + __expf(2.f * x)); }

// ---------------- prep kernels ----------------

__global__ __launch_bounds__(512) void pack_w(const float* __restrict__ Wf,
                                              const float* __restrict__ Wi,
                                              const float* __restrict__ Wo,
                                              const float* __restrict__ Wc,
                                              unsigned short* __restrict__ Wht,
                                              unsigned short* __restrict__ Wxt) {
  __shared__ float tile[64][65];
  int bx = blockIdx.x;
  int g  = bx & 3; bx >>= 2;
  int jb = bx & 15;
  int kb = bx >> 4;
  int j0 = jb * 64, k0 = kb * 64;
  const float* W = (g == 0) ? Wf : (g == 1) ? Wi : (g == 2) ? Wo : Wc;
  int t = threadIdx.x;
  {
    int r  = t >> 3;
    int c0 = (t & 7) * 8;
    const float* src = W + (size_t)(k0 + r) * 1024 + j0 + c0;
    float4 a = *(const float4*)src;
    float4 b = *(const float4*)(src + 4);
    tile[r][c0 + 0] = a.x; tile[r][c0 + 1] = a.y; tile[r][c0 + 2] = a.z; tile[r][c0 + 3] = a.w;
    tile[r][c0 + 4] = b.x; tile[r][c0 + 5] = b.y; tile[r][c0 + 6] = b.z; tile[r][c0 + 7] = b.w;
  }
  __syncthreads();
  {
    int jj  = t >> 3;
    int cc8 = t & 7;
    unsigned short v[8];
#pragma unroll
    for (int e = 0; e < 8; ++e) v[e] = f2b(tile[cc8 * 8 + e][jj]);
    size_t p = (size_t)(4 * (j0 + jj) + g);
    if (k0 < 1024)
      *(uint4*)(&Wht[p * 1024 + k0 + cc8 * 8]) = *(const uint4*)v;
    else
      *(uint4*)(&Wxt[p * 1024 + (k0 - 1024) + cc8 * 8]) = *(const uint4*)v;
  }
}

__global__ __launch_bounds__(256) void pack_bias(const float* __restrict__ bf,
                                                 const float* __restrict__ bi,
                                                 const float* __restrict__ bo,
                                                 const float* __restrict__ bc,
                                                 float* __restrict__ bp) {
  int p = blockIdx.x * 256 + threadIdx.x;
  if (p < 4096) {
    int j = p >> 2, g = p & 3;
    const float* b = (g == 0) ? bf : (g == 1) ? bi : (g == 2) ? bo : bc;
    bp[p] = b[j];
  }
}

__global__ __launch_bounds__(256) void conv_x(const float* __restrict__ x,
                                              unsigned short* __restrict__ xb, int n8) {
  int i = blockIdx.x * 256 + threadIdx.x;
  if (i < n8) {
    const float4* xp = (const float4*)x + (size_t)i * 2;
    float4 a = xp[0], b = xp[1];
    unsigned short v[8] = {f2b(a.x), f2b(a.y), f2b(a.z), f2b(a.w),
                           f2b(b.x), f2b(b.y), f2b(b.z), f2b(b.w)};
    *(uint4*)(&xb[(size_t)i * 8]) = *(const uint4*)v;
  }
}

// zero hA (swizzled layout; zeros are layout-invariant), cst, flagw, gxcnt, flags4
__global__ __launch_bounds__(256) void init_state(unsigned short* __restrict__ hA,
                                                  float* __restrict__ c,
                                                  int* __restrict__ flagw,
                                                  int* __restrict__ gxcnt,
                                                  int* __restrict__ flags4) {
  int i = blockIdx.x * 256 + threadIdx.x;
  if (i < NBAT * 1024) { hA[i] = 0; c[i] = 0.f; }
  if (i < 512) flagw[i] = 0;
  if (i < 256) gxcnt[i] = 0;
  if (i < 4)   flags4[i] = 0;
}

// ---------------- fused persistent kernel ----------------
// grid 256 x 256 thr; LDS 136.3 KB -> 1 block/CU -> all 256 blocks co-resident.

__global__ __launch_bounds__(256, 1) void lstm_fused(
    const unsigned short* __restrict__ Wht,   // [4096][1024] bf16, p = 4*j+g
    const unsigned short* __restrict__ Wxt,   // [4096][1024] bf16
    const float* __restrict__ bp,             // [4096] packed bias
    const unsigned short* __restrict__ xb,    // [512][64][1024] bf16
    float* __restrict__ GxRing,               // [RING][64][4096] fp32
    unsigned short* __restrict__ hA,          // 128KB swizzled h ping
    unsigned short* __restrict__ hB,          // 128KB swizzled h pong
    float* __restrict__ cst,
    float* __restrict__ out,                  // [512][64][1024] fp32
    float* __restrict__ outH,
    float* __restrict__ outC,
    int* __restrict__ flagw,                  // [4][128] per-wave-lane flags
    int* __restrict__ gxcnt,                  // [256]
    int* __restrict__ flags4) {               // [4] block-0 per-wave progress
  __shared__ __align__(16) char lds[139584];

  const int tid = threadIdx.x;
  const int bid = blockIdx.x;
  const int lane = tid & 63;

  if (bid < 128) {
    // ================= recurrence role =================
    unsigned short* Ws = (unsigned short*)lds;             // [32][1024] swizzled, 64 KB
    char*           Ab = lds + 65536;                      // ring4 x 4 waves x 4KB, 64 KB
    float (*G)[33]     = (float(*)[33])(lds + 131072);     // [64][33], 8.4 KB

    const int w   = tid >> 6;
    const int w16 = w * 16;
    const int rl  = lane & 15;
    const int kb  = lane >> 4;
    const int p0  = bid * 32;

    // ---- stage Ws once for the whole sequence ----
    {
      const unsigned short* Wsrc = Wht + (size_t)p0 * 1024;
#pragma unroll
      for (int r = 0; r < 16; ++r) {
        int s = r * 256 + tid;
        int row = s >> 7;
        int slot = s & 127;
        int sub = (slot & 7) ^ (row & 7);
        gld_lds16(Wsrc + (size_t)row * 1024 + ((slot & ~7) | sub) * 8,
                  Ws + (size_t)(r * 256 + (tid & 192)) * 8);
      }
    }

    const int gb   = tid >> 2;            // batch row; wave-local: gb in [16w,16w+16)
    const int gjl  = (tid & 3) * 2;
    const int gidx = gb * 1024 + (p0 >> 2) + gjl;
    float c0 = cst[gidx], c1 = cst[gidx + 1];

    // pre-swizzled publish offset for this thread's dword:
    // region (w=gb>>4, c=bid>>4) * 4096B + entry j*16 + (tid&3)*4,
    // j = (gb&15)*16 + ((bid&15) ^ (gb&7))
    const int hoff = (((gb >> 4) * 8 + (bid >> 4)) << 12) +
                     ((((gb & 15) << 4) + ((bid & 15) ^ (gb & 7))) << 4) +
                     ((tid & 3) << 2);

    asm volatile("s_waitcnt vmcnt(0)" ::: "memory");
    __syncthreads();     // one-time: Ws visible to all waves

    const int fbase = w * 128;   // this wave-lane's flag row

// contiguous ingest: region (w, c_) is 4KB in consumer-read order
#define ASTAGE(c_)                                                             \
    {                                                                          \
      const char* hcc = hsrc + ((w * 8 + (c_)) << 12) + lane * 16;             \
      char* dbase = Ab + ((c_) & 3) * 16384 + w * 4096;                        \
      gld_lds16_sc1(hcc,        dbase);                                        \
      gld_lds16_sc1(hcc + 1024, dbase + 1024);                                 \
      gld_lds16_sc1(hcc + 2048, dbase + 2048);                                 \
      gld_lds16_sc1(hcc + 3072, dbase + 3072);                                 \
    }

    for (int t = 0; t < SEQ; ++t) {
      const char* hsrc = (const char*)((t & 1) ? hB : hA);
      char*       hdst = (char*)((t & 1) ? hA : hB);

      // ---- readiness: each wave polls ITS lane's 128 flags + gxcnt ----
      {
        while (true) {
          int m0 = __hip_atomic_load(&flagw[fbase + lane * 2],     __ATOMIC_RELAXED, __HIP_MEMORY_SCOPE_AGENT);
          int m1 = __hip_atomic_load(&flagw[fbase + lane * 2 + 1], __ATOMIC_RELAXED, __HIP_MEMORY_SCOPE_AGENT);
          int cg = __hip_atomic_load(&gxcnt[t >> 1],               __ATOMIC_RELAXED, __HIP_MEMORY_SCOPE_AGENT);
          if (__all((m0 >= t) && (m1 >= t) && (cg >= 32))) break;
          __builtin_amdgcn_s_sleep(1);
        }
      }
      __builtin_amdgcn_sched_barrier(0);

      // ---- Gx loads (sc1, ring) — oldest vmem ops for the ladder ----
      u32x4 gxa, gxb;
      {
        const float* gsrc = GxRing + (size_t)(t & (RING - 1)) * 262144 +
                            (size_t)gb * 4096 + p0 + gjl * 4;
        asm volatile("global_load_dwordx4 %0, %1, off sc1" : "=v"(gxa) : "v"(gsrc));
        asm volatile("global_load_dwordx4 %0, %1, off offset:16 sc1" : "=v"(gxb) : "v"(gsrc));
      }
      __builtin_amdgcn_sched_barrier(0);

      // ---- staging prologue: chunks 0..3 (wave-private, sc1, contiguous) ----
      ASTAGE(0); ASTAGE(1); ASTAGE(2); ASTAGE(3);

      f32x4 acc0 = (f32x4){0.f, 0.f, 0.f, 0.f};
      f32x4 acc1 = (f32x4){0.f, 0.f, 0.f, 0.f};

#pragma unroll
      for (int kc = 0; kc < 8; ++kc) {
        if      (kc <= 4) asm volatile("s_waitcnt vmcnt(12)" ::: "memory");
        else if (kc == 5) asm volatile("s_waitcnt vmcnt(8)"  ::: "memory");
        else if (kc == 6) asm volatile("s_waitcnt vmcnt(4)"  ::: "memory");
        else              asm volatile("s_waitcnt vmcnt(0)"  ::: "memory");
        __builtin_amdgcn_sched_barrier(0);
        const char* Abc = Ab + (kc & 3) * 16384 + w * 4096;
#pragma unroll
        for (int ks = 0; ks < 4; ++ks) {
          int g = ks * 4 + kb;
          short8 af = *(const short8*)(Abc + rl * 256 + ((g ^ (rl & 7)) * 16));
          int gslot = kc * 16 + g;
          int gbase = (gslot & ~7) * 16;
          short8 bf0 = *(const short8*)((const char*)Ws + (0 * 16 + rl) * 2048 + gbase +
                                        (((gslot & 7) ^ (rl & 7)) * 16));
          short8 bf1 = *(const short8*)((const char*)Ws + (1 * 16 + rl) * 2048 + gbase +
                                        (((gslot & 7) ^ (rl & 7)) * 16));
          acc0 = __builtin_amdgcn_mfma_f32_16x16x32_bf16(af, bf0, acc0, 0, 0, 0);
          acc1 = __builtin_amdgcn_mfma_f32_16x16x32_bf16(af, bf1, acc1, 0, 0, 0);
        }
        if (kc + 4 < 8) ASTAGE(kc + 4);
      }

      // ---- acc -> G (wave-local quarter), gates (same wave reads it) ----
#pragma unroll
      for (int r = 0; r < 4; ++r) {
        G[w16 + kb * 4 + r][rl]      = acc0[r];
        G[w16 + kb * 4 + r][16 + rl] = acc1[r];
      }
      f32x4 gx0 = __builtin_bit_cast(f32x4, gxa);
      f32x4 gx1 = __builtin_bit_cast(f32x4, gxb);
      float f0 = sigf(G[gb][gjl * 4 + 0] + gx0[0]);
      float i0 = sigf(G[gb][gjl * 4 + 1] + gx0[1]);
      float o0 = sigf(G[gb][gjl * 4 + 2] + gx0[2]);
      float q0 = tanhfast(G[gb][gjl * 4 + 3] + gx0[3]);
      float f1 = sigf(G[gb][gjl * 4 + 4] + gx1[0]);
      float i1 = sigf(G[gb][gjl * 4 + 5] + gx1[1]);
      float o1 = sigf(G[gb][gjl * 4 + 6] + gx1[2]);
      float q1 = tanhfast(G[gb][gjl * 4 + 7] + gx1[3]);
      c0 = c0 * f0 + q0 * i0;
      c1 = c1 * f1 + q1 * i1;
      float h0 = tanhfast(c0) * o0;
      float h1 = tanhfast(c1) * o1;

      // ---- release: h publish (sc1, pre-swizzled addr) -> ack -> flag ----
      __hip_atomic_store((unsigned*)(hdst + hoff),
                         ((unsigned)f2b(h1) << 16) | (unsigned)f2b(h0),
                         __ATOMIC_RELAXED, __HIP_MEMORY_SCOPE_AGENT);
      asm volatile("s_waitcnt vmcnt(0)" ::: "memory");
      if (lane == 0) {
        __hip_atomic_store(&flagw[fbase + bid], t + 1, __ATOMIC_RELAXED, __HIP_MEMORY_SCOPE_AGENT);
        if (bid == 0)
          __hip_atomic_store(&flags4[w], t + 1, __ATOMIC_RELAXED, __HIP_MEMORY_SCOPE_AGENT);
      }

      // off the critical path: out / tails; drain acks in dead time so the
      // next step's KWAIT counts stay exact
      *(float2*)&out[(size_t)t * 65536 + gidx] = make_float2(h0, h1);
      if (t == SEQ - 1) {
        *(float2*)&outH[gidx] = make_float2(h0, h1);
        *(float2*)&outC[gidx] = make_float2(c0, c1);
      }
      asm volatile("s_waitcnt vmcnt(0)" ::: "memory");
    }
#undef ASTAGE

    cst[gidx]     = c0;
    cst[gidx + 1] = c1;

  } else {
    // ================= GEMM worker role =================
    unsigned short* AsW = (unsigned short*)lds;            // [2][8192]
    unsigned short* BsW = (unsigned short*)(lds + 32768);  // [2][8192]
    const int wid = bid - 128;
    const int w = tid >> 6;
    const int rl = lane & 15, kb = lane >> 4;
    const int wr = w >> 1, wc = w & 1;

    for (int tau = wid; tau < 8192; tau += 128) {
      int sp = tau >> 5;         // step pair 0..255
      int bn = tau & 31;         // 128-col tile

      // ring-overwrite gate (margin 16 steps; min over per-wave progress)
      if (2 * sp >= RING - 16) {
        int need = 2 * sp - (RING - 16) + 1;
        while (true) {
          int v = __hip_atomic_load(&flags4[lane & 3], __ATOMIC_RELAXED, __HIP_MEMORY_SCOPE_AGENT);
          if (__all(v >= need)) break;
          __builtin_amdgcn_s_sleep(16);
        }
      }

      const unsigned short* Abase = xb + (size_t)sp * 131072;
      const unsigned short* Bbase = Wxt + (size_t)bn * 131072;

      f32x4 acc[4][4];
#pragma unroll
      for (int m = 0; m < 4; ++m)
#pragma unroll
        for (int n = 0; n < 4; ++n) acc[m][n] = (f32x4){0.f, 0.f, 0.f, 0.f};

#define GSTAGE(k0_, buf_)                                                       \
      {                                                                         \
        _Pragma("unroll") for (int r = 0; r < 4; ++r) {                         \
          int i = r * 256 + tid;                                                \
          int row = i >> 3;                                                     \
          int cc = (i & 7) ^ (row & 7);                                         \
          int base = (r * 256 + (tid & 192)) * 8;                               \
          gld_lds16(Abase + (size_t)row * 1024 + (k0_) + cc * 8, &AsW[(buf_)*8192 + base]); \
          gld_lds16(Bbase + (size_t)row * 1024 + (k0_) + cc * 8, &BsW[(buf_)*8192 + base]); \
        }                                                                       \
      }

      GSTAGE(0, 0);
      __syncthreads();
      int cur = 0;
#pragma unroll 2
      for (int kc = 0; kc < 16; ++kc) {
        if (kc < 15) GSTAGE((kc + 1) * 64, cur ^ 1);
        const char* Abt = (const char*)&AsW[cur * 8192];
        const char* Bbt = (const char*)&BsW[cur * 8192];
#pragma unroll
        for (int ks = 0; ks < 2; ++ks) {
          int g = ks * 4 + kb;
          short8 bf[4], af[4];
#pragma unroll
          for (int nt = 0; nt < 4; ++nt) {
            int brow = wc * 64 + nt * 16 + rl;
            bf[nt] = *(const short8*)(Bbt + brow * 128 + ((g ^ (brow & 7)) * 16));
          }
#pragma unroll
          for (int mt = 0; mt < 4; ++mt) {
            int arow = wr * 64 + mt * 16 + rl;
            af[mt] = *(const short8*)(Abt + arow * 128 + ((g ^ (arow & 7)) * 16));
          }
#pragma unroll
          for (int mt = 0; mt < 4; ++mt)
#pragma unroll
            for (int nt = 0; nt < 4; ++nt)
              acc[mt][nt] = __builtin_amdgcn_mfma_f32_16x16x32_bf16(af[mt], bf[nt], acc[mt][nt], 0, 0, 0);
        }
        __syncthreads();
        cur ^= 1;
      }
#undef GSTAGE

      // epilogue: device-scope stores into the ring (+bias)
      float* Cb = GxRing + (size_t)((2 * sp) & (RING - 1)) * 262144;
#pragma unroll
      for (int nt = 0; nt < 4; ++nt) {
        int p = bn * 128 + wc * 64 + nt * 16 + rl;
        float bias = bp[p];
#pragma unroll
        for (int mt = 0; mt < 4; ++mt) {
#pragma unroll
          for (int r = 0; r < 4; ++r) {
            int row = wr * 64 + mt * 16 + kb * 4 + r;   // 0..127 within the pair
            __hip_atomic_store(&Cb[(size_t)row * 4096 + p], acc[mt][nt][r] + bias,
                               __ATOMIC_RELAXED, __HIP_MEMORY_SCOPE_AGENT);
          }
        }
      }
      asm volatile("s_waitcnt vmcnt(0)" ::: "memory");
      __syncthreads();
      if (tid == 0)
        __hip_atomic_fetch_add(&gxcnt[sp], 1, __ATOMIC_RELAXED, __HIP_MEMORY_SCOPE_AGENT);
    }
  }
}

// ---------------- launch ----------------

extern "C" void kernel_launch(void* const* d_in, const int* in_sizes, int n_in,
                              void* d_out, int out_size, void* d_ws, size_t ws_size,
                              hipStream_t stream) {
  const float* x  = (const float*)d_in[0];
  const float* Wf = (const float*)d_in[1];
  const float* bf = (const float*)d_in[2];
  const float* Wi = (const float*)d_in[3];
  const float* bi = (const float*)d_in[4];
  const float* Wo = (const float*)d_in[5];
  const float* bo = (const float*)d_in[6];
  const float* Wc = (const float*)d_in[7];
  const float* bc = (const float*)d_in[8];
  float* out = (float*)d_out;

  char* ws = (char*)d_ws;
  unsigned short* Wht = (unsigned short*)(ws);                 //  8,388,608
  unsigned short* Wxt = (unsigned short*)(ws + 8388608);       //  8,388,608
  float*          bp  = (float*)(ws + 16777216);               //     16,384
  unsigned short* xb  = (unsigned short*)(ws + 16793600);      // 67,108,864
  unsigned short* hA  = (unsigned short*)(ws + 83902464);      //    131,072 (swizzled)
  unsigned short* hB  = (unsigned short*)(ws + 84033536);      //    131,072 (swizzled)
  float*          cst = (float*)(ws + 84164608);               //    262,144
  int*            flw = (int*)(ws + 84426752);                 //      2,048 (pad 4K)
  int*            gxc = (int*)(ws + 84430848);                 //      1,024
  int*            fl4 = (int*)(ws + 84431872);                 //         16 (pad to 84440064)
  float*          GxR = (float*)(ws + 84440064);               // 134,217,728

  pack_w    <<<2048,  512, 0, stream>>>(Wf, Wi, Wo, Wc, Wht, Wxt);
  pack_bias <<<16,    256, 0, stream>>>(bf, bi, bo, bc, bp);
  conv_x    <<<16384, 256, 0, stream>>>(x, xb, 4194304);
  init_state<<<256,   256, 0, stream>>>(hA, cst, flw, gxc, fl4);

  float* outH = out + (size_t)SEQ * NBAT * 1024;
  float* outC = outH + NBAT * 1024;

  lstm_fused<<<256, 256, 0, stream>>>(Wht, Wxt, bp, xb, GxR, hA, hB, cst,
                                      out, outH, outC, flw, gxc, fl4);
}